// Round 14
// baseline (232.890 us; speedup 1.0000x reference)
//
#include <hip/hip_runtime.h>

#define BSZ  4
#define QL   256
#define KVL  2048
#define HIST 1792
#define WIN  1024
#define NH   32
#define NKVH 8
#define DH   128
#define HID  4096
#define SCALE 0.088388347648318447f
#define MFIX  8.0f

typedef __bf16 bf16x8 __attribute__((ext_vector_type(8)));
typedef float  fx4    __attribute__((ext_vector_type(4)));
typedef unsigned short us4 __attribute__((ext_vector_type(4)));
typedef unsigned short us8 __attribute__((ext_vector_type(8)));

__device__ __forceinline__ unsigned short f2bf(float x) {
    unsigned u = __float_as_uint(x);
    u += 0x7FFFu + ((u >> 16) & 1u);   // round-to-nearest-even
    return (unsigned short)(u >> 16);
}
__device__ __forceinline__ float bf2f(unsigned short h) {
    return __uint_as_float(((unsigned)h) << 16);
}
__device__ __forceinline__ fx4 mfma16(bf16x8 a, bf16x8 b, fx4 c) {
    return __builtin_amdgcn_mfma_f32_16x16x32_bf16(a, b, c, 0, 0, 0);
}
__device__ __forceinline__ bf16x8 ldb16(const unsigned short* p) {
    return *reinterpret_cast<const bf16x8*>(p);
}

typedef __attribute__((address_space(1))) const void gv_t;
typedef __attribute__((address_space(3))) void lv_t;
__device__ __forceinline__ void gl16(const void* g, void* l) {
    __builtin_amdgcn_global_load_lds((gv_t*)g, (lv_t*)l, 16, 0, 0);
}

// ---------------------------------------------------------------------------
// bf16 GEMM body: C = A[M x K] @ B^T, 128x128 tile, BK=32, mfma_16x16x32.
// A is row-major [M][K]; B^T is BLOCKED: [n_blk][k_blk][64n][64k] bf16
// (8KB contiguous per 64x64 tile) -- producer (transpose) writes 1KB-
// contiguous, consumer computes per-lane global_load_lds source addresses.
// 3-buffer depth-2 pipeline (counted vmcnt, raw barriers), XCD swizzle,
// split-K over bz.
// ---------------------------------------------------------------------------
__device__ __forceinline__ void gemm_body(
    const unsigned short* __restrict__ A, const unsigned short* __restrict__ B,
    float* __restrict__ C0, float* __restrict__ Cz, size_t czstride,
    int lda, int ldc, int ksteps, int klast, int nx, int ny, int nz)
{
    constexpr int TILE = 128 * 32;            // ushorts per operand tile
    __shared__ __align__(16) unsigned short lds[3 * 2 * TILE];   // 48 KB

    const int per = gridDim.x >> 3;
    const int t = (blockIdx.x & 7) * per + (blockIdx.x >> 3);
    const int bx = t % nx;
    const int by = (t / nx) % ny;
    const int bz = t / (nx * ny);

    const int row0 = bx * 128;
    const int col0 = by * 128;
    const int kbase = bz * ksteps * 32;
    const int nks = (bz == nz - 1) ? klast : ksteps;
    float* Cm = (bz == 0) ? C0 : (Cz + (size_t)(bz - 1) * czstride);

    const int tid  = threadIdx.x;
    const int lane = tid & 63;
    const int w    = tid >> 6;
    const int wr   = w >> 1, wc = w & 1;
    const int l16  = lane & 15;
    const int lg   = lane >> 4;
    const int r_in = lane >> 2;          // 0..15
    const int c8   = (lane & 3) * 8;     // 0,8,16,24 (bf16)

    fx4 acc[4][4] = {};

    auto STAGE = [&](int bufi, int kp) {
        unsigned short* Lb = lds + bufi * (2 * TILE);
#pragma unroll
        for (int i = 0; i < 2; ++i) {
            const int r = w * 32 + i * 16 + r_in;
            const int ldsb = (w * 2 + i) * 512;
            gl16(A + (size_t)(row0 + r) * lda + kp + c8, Lb + ldsb);
            const int cr = col0 + r;
            const size_t baddr = ((size_t)(cr >> 6) * 64 + (kp >> 6)) * 4096
                               + (cr & 63) * 64 + (kp & 63) + c8;
            gl16(B + baddr, Lb + TILE + ldsb);
        }
    };

    STAGE(0, kbase);
    STAGE(1, kbase + 32);
    for (int ks = 0; ks < nks; ++ks) {
        if (ks + 2 < nks) {
            STAGE((ks + 2) % 3, kbase + (ks + 2) * 32);
            asm volatile("s_waitcnt vmcnt(8)" ::: "memory");   // tile ks done
        } else if (ks + 1 < nks) {
            asm volatile("s_waitcnt vmcnt(4)" ::: "memory");
        } else {
            asm volatile("s_waitcnt vmcnt(0)" ::: "memory");
        }
        __builtin_amdgcn_s_barrier();
        __builtin_amdgcn_sched_barrier(0);

        const unsigned short* Lb = lds + (ks % 3) * (2 * TILE);
        const unsigned short* AhT = Lb;
        const unsigned short* BhT = Lb + TILE;

        bf16x8 af[4], bfv[4];
#pragma unroll
        for (int f = 0; f < 4; ++f) {
            af[f]  = ldb16(AhT + (wr * 64 + f * 16 + l16) * 32 + lg * 8);
            bfv[f] = ldb16(BhT + (wc * 64 + f * 16 + l16) * 32 + lg * 8);
        }
        __builtin_amdgcn_s_setprio(1);
#pragma unroll
        for (int fr = 0; fr < 4; ++fr)
#pragma unroll
            for (int fc = 0; fc < 4; ++fc)
                acc[fr][fc] = mfma16(af[fr], bfv[fc], acc[fr][fc]);
        __builtin_amdgcn_s_setprio(0);
        __builtin_amdgcn_sched_barrier(0);
        __builtin_amdgcn_s_barrier();
    }
#pragma unroll
    for (int fr = 0; fr < 4; ++fr)
#pragma unroll
        for (int fc = 0; fc < 4; ++fc) {
            const size_t rbase = (size_t)(row0 + wr * 64 + fr * 16 + lg * 4);
            const int col = col0 + wc * 64 + fc * 16 + l16;
#pragma unroll
            for (int r = 0; r < 4; ++r)
                Cm[(rbase + r) * ldc + col] = acc[fr][fc][r];
        }
}

__global__ __launch_bounds__(256) void qkv_gemm_kernel(
    const unsigned short* __restrict__ A, const unsigned short* __restrict__ B,
    float* __restrict__ C0, float* __restrict__ Cz, size_t czstride,
    int lda, int ldc, int ksteps, int klast, int nx, int ny, int nz)
{
    gemm_body(A, B, C0, Cz, czstride, lda, ldc, ksteps, klast, nx, ny, nz);
}

__global__ __launch_bounds__(256) void oproj_gemm_kernel(
    const unsigned short* __restrict__ A, const unsigned short* __restrict__ B,
    float* __restrict__ C0, float* __restrict__ Cz, size_t czstride,
    int lda, int ldc, int ksteps, int klast, int nx, int ny, int nz)
{
    gemm_body(A, B, C0, Cz, czstride, lda, ldc, ksteps, klast, nx, ny, nz);
}

// ---------------------------------------------------------------------------
// Prep mega-kernel: 4 weight transposes + hs convert + sincos table.
// Transpose: f32 XOR-swizzled LDS (shf[n][k ^ (n&28)], write 2-way free,
// read uniform 8/bank = floor); OUTPUT IS BLOCKED [n_blk][k_blk][64][64]
// bf16 so each store instruction writes 1KB contiguous (was 16x64B scatter).
// ---------------------------------------------------------------------------
__device__ __forceinline__ void transpose_tile(
    const float* __restrict__ w, unsigned short* __restrict__ hi, int N,
    int n0, int k0)
{
    __shared__ __align__(16) float shf[64][64];   // 16 KB, XOR-swizzled
    const int tid = threadIdx.x;
    const int rr = tid >> 4;            // 0..15
    const int cc = (tid & 15) * 4;      // 0..60
#pragma unroll
    for (int p = 0; p < 4; ++p) {
        const int kl = p * 16 + rr;
        fx4 v = *reinterpret_cast<const fx4*>(w + (size_t)(k0 + kl) * N + n0 + cc);
#pragma unroll
        for (int j = 0; j < 4; ++j) {
            const int n = cc + j;
            shf[n][kl ^ (n & 28)] = v[j];
        }
    }
    __syncthreads();
    // blocked output: tile (n0,k0) -> 8KB block at ((n0/64)*64 + k0/64)*4096
    unsigned short* ob = hi + (((size_t)(n0 >> 6)) * 64 + (k0 >> 6)) * 4096;
#pragma unroll
    for (int s = 0; s < 2; ++s) {
        const int c = s * 256 + tid;      // chunk 0..511 (8 shorts each)
        const int n = c >> 3;
        const int k8 = (c & 7) * 8;
        const int sw = n & 28;
        const int b0 = (k8 ^ (sw & 24)) | (sw & 4);
        fx4 v0 = *reinterpret_cast<const fx4*>(&shf[n][b0]);      // k8..k8+3
        fx4 v1 = *reinterpret_cast<const fx4*>(&shf[n][b0 ^ 4]);  // k8+4..k8+7
        us8 o;
#pragma unroll
        for (int j = 0; j < 4; ++j) {
            o[j]     = f2bf(v0[j]);
            o[4 + j] = f2bf(v1[j]);
        }
        *reinterpret_cast<us8*>(ob + c * 8) = o;   // 64 lanes x 16B = 1KB contiguous
    }
}

__global__ __launch_bounds__(256) void prep_kernel(
    const float* __restrict__ wq, const float* __restrict__ wk,
    const float* __restrict__ wv, const float* __restrict__ wo,
    const float* __restrict__ hs,
    unsigned short* __restrict__ wqkvT, unsigned short* __restrict__ woTh,
    unsigned short* __restrict__ hsb, float* __restrict__ tab)
{
    const int r = blockIdx.x;
    const int tid = threadIdx.x;
    if (r < 4096) {
        transpose_tile(wq, wqkvT, 4096, (r & 63) * 64, (r >> 6) * 64);
    } else if (r < 5120) {
        const int r2 = r - 4096;
        transpose_tile(wk, wqkvT + (size_t)4096 * 4096, 1024,
                       (r2 & 15) * 64, (r2 >> 4) * 64);
    } else if (r < 6144) {
        const int r2 = r - 5120;
        transpose_tile(wv, wqkvT + (size_t)5120 * 4096, 1024,
                       (r2 & 15) * 64, (r2 >> 4) * 64);
    } else if (r < 10240) {
        const int r2 = r - 6144;
        transpose_tile(wo, woTh, 4096, (r2 & 63) * 64, (r2 >> 6) * 64);
    } else if (r < 12288) {
        const int r2 = r - 10240;
        int i = r2 * 256 + tid;
#pragma unroll
        for (int rep = 0; rep < 2; ++rep) {
            fx4 v = reinterpret_cast<const fx4*>(hs)[i];
            us4 o;
#pragma unroll
            for (int j = 0; j < 4; ++j) o[j] = f2bf(v[j]);
            reinterpret_cast<us4*>(hsb)[i] = o;
            i += 524288;
        }
    } else {
        const int r2 = r - 12288;
        const int qi = r2 * 4 + (tid >> 6);
        const int jr = tid & 63;
        const float inv = powf(10000.f, -(float)jr * (1.f / 64.f));
        const float f = (float)(HIST + qi) * inv;
        float s, c;
        sincosf(f, &s, &c);
        tab[(qi * 64 + jr) * 2]     = c;
        tab[(qi * 64 + jr) * 2 + 1] = s;
    }
}

// ---------------------------------------------------------------------------
// RoPE on Q (adds split-K partials) -> bf16 [B][H][Q][D]
// ---------------------------------------------------------------------------
__global__ __launch_bounds__(256) void rope_q_kernel(
    const float* __restrict__ qkv0, const float* __restrict__ qkv1,
    const int* __restrict__ pos_ids, const float* __restrict__ tab,
    unsigned short* __restrict__ qb)
{
    const int t = blockIdx.x;             // 0..1023
    const int b = t >> 8;
    const int qi = t & 255;
    const int pi = pos_ids[t] - HIST;     // 0..255
    const int tid = threadIdx.x;
    const int h = tid >> 3;               // 0..31
    const int d0 = (tid & 7) * 8;         // 0..56
    const float* q0 = qkv0 + (size_t)t * 6144 + h * DH;
    const float* q1 = qkv1 + (size_t)t * 6144 + h * DH;
    float xl[8], xh[8];
    *reinterpret_cast<fx4*>(&xl[0]) = *reinterpret_cast<const fx4*>(q0 + d0)
                                    + *reinterpret_cast<const fx4*>(q1 + d0);
    *reinterpret_cast<fx4*>(&xl[4]) = *reinterpret_cast<const fx4*>(q0 + d0 + 4)
                                    + *reinterpret_cast<const fx4*>(q1 + d0 + 4);
    *reinterpret_cast<fx4*>(&xh[0]) = *reinterpret_cast<const fx4*>(q0 + d0 + 64)
                                    + *reinterpret_cast<const fx4*>(q1 + d0 + 64);
    *reinterpret_cast<fx4*>(&xh[4]) = *reinterpret_cast<const fx4*>(q0 + d0 + 68)
                                    + *reinterpret_cast<const fx4*>(q1 + d0 + 68);
    us8 outl, outh;
#pragma unroll
    for (int i = 0; i < 8; ++i) {
        const int jr = d0 + i;
        const float c = tab[(pi * 64 + jr) * 2];
        const float s = tab[(pi * 64 + jr) * 2 + 1];
        outl[i] = f2bf(xl[i] * c - xh[i] * s);
        outh[i] = f2bf(xh[i] * c + xl[i] * s);
    }
    unsigned short* dst = qb + (((size_t)b * NH + h) * QL + qi) * DH;
    *reinterpret_cast<us8*>(dst + d0)      = outl;
    *reinterpret_cast<us8*>(dst + d0 + 64) = outh;
}

// ---------------------------------------------------------------------------
// Gather KV, fully vectorized (float4 loads, 8 lanes/token), XCD-grouped.
//   k_all: [B][KVH][64 tiles][16 dchunks][32 kv][8] bf16 (chunked tiles)
//   vT:    [B][KVH][64 tiles][4 kvchunks][128 d][8 kv] bf16 (chunked tiles)
// ---------------------------------------------------------------------------
__global__ __launch_bounds__(256) void gather_kv_kernel(
    const float* __restrict__ qkv0, const float* __restrict__ qkv1,
    const float* __restrict__ k_cache, const float* __restrict__ v_cache,
    const int* __restrict__ block_offsets, const float* __restrict__ tab,
    unsigned short* __restrict__ k_all, unsigned short* __restrict__ vT)
{
    __shared__ unsigned short vls[32][136];
    const int bid = blockIdx.x;
    const int xcd = bid & 7;
    const int i = bid >> 3;               // 0..255
    const int g = ((i & 31) << 3) | xcd;  // token-chunk group
    const int kh = i >> 5;                // 0..7
    const int b  = g >> 6;
    const int ck = g & 63;
    const int kv0 = ck * 32;
    const int tid = threadIdx.x;
    const int tok = tid >> 3;             // 0..31
    const int sl  = tid & 7;              // 0..7 (d-slice)
    const int kvpos = kv0 + tok;
    const bool is_old = (kvpos < HIST);

    float x[16];
    float v[16];
    if (is_old) {
        const int blk = block_offsets[b * 32 + (kvpos >> 6)];
        const size_t base = (((size_t)blk * 64 + (kvpos & 63)) * NKVH + kh) * DH + sl * 4;
        const float* sk = k_cache + base;
        const float* sv = v_cache + base;
#pragma unroll
        for (int j = 0; j < 4; ++j) {
            *reinterpret_cast<fx4*>(&x[j * 4]) = *reinterpret_cast<const fx4*>(sk + j * 32);
            *reinterpret_cast<fx4*>(&v[j * 4]) = *reinterpret_cast<const fx4*>(sv + j * 32);
        }
    } else {
        const int t = b * QL + (kvpos - HIST);
        const int pi = kvpos - HIST;
        const size_t tb = (size_t)t * 6144 + kh * DH + sl * 4;
        const float* k0p = qkv0 + tb + 4096;
        const float* k1p = qkv1 + tb + 4096;
        const float* v0p = qkv0 + tb + 5120;
        const float* v1p = qkv1 + tb + 5120;
#pragma unroll
        for (int j = 0; j < 4; ++j) {
            *reinterpret_cast<fx4*>(&x[j * 4]) =
                *reinterpret_cast<const fx4*>(k0p + j * 32) +
                *reinterpret_cast<const fx4*>(k1p + j * 32);
            *reinterpret_cast<fx4*>(&v[j * 4]) =
                *reinterpret_cast<const fx4*>(v0p + j * 32) +
                *reinterpret_cast<const fx4*>(v1p + j * 32);
        }
#pragma unroll
        for (int j = 0; j < 2; ++j) {
            const int jr0 = sl * 4 + j * 32;
            fx4 cs0 = *reinterpret_cast<const fx4*>(tab + ((size_t)pi * 64 + jr0) * 2);
            fx4 cs1 = *reinterpret_cast<const fx4*>(tab + ((size_t)pi * 64 + jr0) * 2 + 4);
            const float c[4] = {cs0[0], cs0[2], cs1[0], cs1[2]};
            const float s[4] = {cs0[1], cs0[3], cs1[1], cs1[3]};
#pragma unroll
            for (int e = 0; e < 4; ++e) {
                const float lo = x[j * 4 + e], hi = x[(j + 2) * 4 + e];
                x[j * 4 + e]       = lo * c[e] - hi * s[e];
                x[(j + 2) * 4 + e] = hi * c[e] + lo * s[e];
            }
        }
    }
    {
        const size_t tbase = (((size_t)b * NKVH + kh) * KVL + kv0) * DH;
#pragma unroll
        for (int j = 0; j < 4; ++j) {
            const int d = sl * 4 + j * 32;
            const int dc = d >> 3;
            us4 pk;
#pragma unroll
            for (int e = 0; e < 4; ++e) pk[e] = f2bf(x[j * 4 + e]);
            *reinterpret_cast<us4*>(k_all + tbase + ((dc * 32 + tok) << 3) + (d & 7)) = pk;
        }
    }
#pragma unroll
    for (int j = 0; j < 4; ++j) {
        us4 pv;
#pragma unroll
        for (int e = 0; e < 4; ++e) pv[e] = f2bf(v[j * 4 + e]);
        *reinterpret_cast<us4*>(&vls[tok][sl * 4 + j * 32]) = pv;
    }
    __syncthreads();
    const int dr = tid >> 1;
    const int half = tid & 1;
    unsigned short* vtile = vT + (((size_t)b * NKVH + kh) * 64 + ck) * 4096;
#pragma unroll
    for (int i2 = 0; i2 < 16; i2 += 8) {
        const int kvc = half * 2 + (i2 >> 3);
        us8 pk;
#pragma unroll
        for (int j = 0; j < 8; ++j) pk[j] = vls[half * 16 + i2 + j][dr];
        *reinterpret_cast<us8*>(vtile + kvc * 1024 + dr * 8) = pk;
    }
}

// ---------------------------------------------------------------------------
// Flash attention (GQA, sliding window) -> bf16 output.
// 512-thread blocks = 2 q-heads sharing staged K/V; pair-processed kv tiles
// (4 LDS buffers, one lgkm fence per pair); fixed-max softmax (M=8);
// per-lane deferred lsum; GQA-aware XCD swizzle.
// ---------------------------------------------------------------------------
__global__ __launch_bounds__(512) void attn_kernel(
    const unsigned short* __restrict__ qb,
    const unsigned short* __restrict__ kall,
    const unsigned short* __restrict__ vT,
    unsigned short* __restrict__ ohi)
{
    __shared__ __align__(16) unsigned short ldskv[4 * 8192];
    __shared__ __align__(16) unsigned short plds[8][16][88];

    const int bid = blockIdx.x;              // 256 blocks
    const int xcd = bid & 7, slot = bid >> 3;
    const int pair = xcd * 4 + (slot >> 3);
    const int within = slot & 7;
    const int kh = pair >> 2, b = pair & 3;
    const int qt = within & 3, p = within >> 2;

    const int tid = threadIdx.x;
    const int lane = tid & 63;
    const int w = tid >> 6;
    const int h = kh * 4 + p * 2 + (w >> 2);
    const int ww = w & 3;
    const int l16 = lane & 15;
    const int lg = lane >> 4;
    const int qrow0 = qt * 64 + ww * 16;
    const int qabs0 = HIST + qrow0;

    const unsigned short* qptr =
        qb + (((size_t)b * NH + h) * QL + qrow0 + l16) * DH + lg * 8;
    bf16x8 qf[4];
#pragma unroll
    for (int ds = 0; ds < 4; ++ds) qf[ds] = ldb16(qptr + ds * 32);

    fx4 oacc[8];
#pragma unroll
    for (int f = 0; f < 8; ++f) oacc[f] = (fx4){0.f, 0.f, 0.f, 0.f};
    float lsum[4] = {0.f, 0.f, 0.f, 0.f};

    const unsigned short* kbase = kall + ((size_t)b * NKVH + kh) * (KVL * DH);
    const unsigned short* vbase = vT + ((size_t)b * NKVH + kh) * (KVL * DH);

    const int kv_lo = ((HIST + qt * 64) - (WIN - 1)) & ~31;   // 34 tiles of 32

    auto STAGE = [&](int bufi, int kv0) {
        unsigned short* kl = ldskv + bufi * 8192;
        const unsigned short* kg = kbase + (size_t)kv0 * DH;
        const unsigned short* vg = vbase + (size_t)(kv0 >> 5) * 4096;
        const int ci = w * 64 + lane;
        gl16(kg + ci * 8, kl + ci * 8);
        gl16(vg + ci * 8, kl + 4096 + ci * 8);
    };

    auto QK = [&](const unsigned short* kl, fx4& s0, fx4& s1) {
#pragma unroll
        for (int ds = 0; ds < 4; ++ds) {
            bf16x8 kf0 = ldb16(kl + ((ds * 4 + lg) * 32 + l16) * 8);
            bf16x8 kf1 = ldb16(kl + ((ds * 4 + lg) * 32 + 16 + l16) * 8);
            s0 = mfma16(qf[ds], kf0, s0);
            s1 = mfma16(qf[ds], kf1, s1);
        }
    };

    auto SM = [&](int kv0, fx4& s0, fx4& s1, int pc) {
        float p0v[4], p1v[4];
        const bool interior = (kv0 >= qabs0 + 16 - WIN) && (kv0 + 31 <= qabs0);
        if (interior) {
#pragma unroll
            for (int r = 0; r < 4; ++r) {
                p0v[r] = __expf(fmaf(s0[r], SCALE, -MFIX));
                p1v[r] = __expf(fmaf(s1[r], SCALE, -MFIX));
            }
        } else {
            const int kvp0 = kv0 + l16, kvp1 = kvp0 + 16;
#pragma unroll
            for (int r = 0; r < 4; ++r) {
                const int qpos = qabs0 + lg * 4 + r;
                const float e0 = __expf(fmaf(s0[r], SCALE, -MFIX));
                const float e1 = __expf(fmaf(s1[r], SCALE, -MFIX));
                p0v[r] = (kvp0 <= qpos && kvp0 > qpos - WIN) ? e0 : 0.f;
                p1v[r] = (kvp1 <= qpos && kvp1 > qpos - WIN) ? e1 : 0.f;
            }
        }
#pragma unroll
        for (int r = 0; r < 4; ++r) {
            lsum[r] += p0v[r] + p1v[r];
            plds[w][lg * 4 + r][pc + l16] = f2bf(p0v[r]);
            plds[w][lg * 4 + r][pc + 16 + l16] = f2bf(p1v[r]);
        }
    };

    auto PV = [&](const unsigned short* vl, bf16x8 pa) {
#pragma unroll
        for (int f = 0; f < 8; ++f) {
            bf16x8 vf = ldb16(vl + lg * 1024 + (f * 16 + l16) * 8);
            oacc[f] = mfma16(pa, vf, oacc[f]);
        }
    };

    STAGE(0, kv_lo);
    STAGE(1, kv_lo + 32);

    for (int t = 0; t < 34; t += 2) {
        if (t + 2 < 34) {
            STAGE((t + 2) & 3, kv_lo + (t + 2) * 32);
            STAGE((t + 3) & 3, kv_lo + (t + 3) * 32);
            asm volatile("s_waitcnt vmcnt(4)" ::: "memory");
        } else {
            asm volatile("s_waitcnt vmcnt(0)" ::: "memory");
        }
        __builtin_amdgcn_s_barrier();
        __builtin_amdgcn_sched_barrier(0);

        const unsigned short* kl0 = ldskv + (t & 3) * 8192;
        const unsigned short* kl1 = ldskv + ((t + 1) & 3) * 8192;

        fx4 sA0 = (fx4){0.f, 0.f, 0.f, 0.f}, sA1 = (fx4){0.f, 0.f, 0.f, 0.f};
        fx4 sB0 = (fx4){0.f, 0.f, 0.f, 0.f}, sB1 = (fx4){0.f, 0.f, 0.f, 0.f};
        __builtin_amdgcn_s_setprio(1);
        QK(kl0, sA0, sA1);
        QK(kl1, sB0, sB1);
        __builtin_amdgcn_s_setprio(0);

        SM(kv_lo + t * 32, sA0, sA1, 0);
        SM(kv_lo + (t + 1) * 32, sB0, sB1, 40);

        asm volatile("s_waitcnt lgkmcnt(0)" ::: "memory");
        __builtin_amdgcn_sched_barrier(0);
        bf16x8 pa0 = ldb16(&plds[w][l16][0 + lg * 8]);
        bf16x8 pa1 = ldb16(&plds[w][l16][40 + lg * 8]);
        __builtin_amdgcn_s_setprio(1);
        PV(kl0 + 4096, pa0);
        PV(kl1 + 4096, pa1);
        __builtin_amdgcn_s_setprio(0);
        __builtin_amdgcn_sched_barrier(0);
        __builtin_amdgcn_s_barrier();
    }
#pragma unroll
    for (int r = 0; r < 4; ++r) {
#pragma unroll
        for (int off = 1; off < 16; off <<= 1)
            lsum[r] += __shfl_xor(lsum[r], off);
    }
    float rl[4];
#pragma unroll
    for (int r = 0; r < 4; ++r) rl[r] = 1.f / lsum[r];
    const size_t obase = ((size_t)b * QL + qrow0 + lg * 4) * (NH * DH) + h * DH;
#pragma unroll
    for (int f = 0; f < 8; ++f)
#pragma unroll
        for (int r = 0; r < 4; ++r)
            ohi[obase + (size_t)r * (NH * DH) + f * 16 + l16] = f2bf(oacc[f][r] * rl[r]);
}

__global__ __launch_bounds__(256) void reduce_out_kernel(
    float* __restrict__ out, const float* __restrict__ parts)
{
    const int n4 = (1024 * 4096) / 4;
    int i = blockIdx.x * blockDim.x + threadIdx.x;
    for (; i < n4; i += gridDim.x * blockDim.x) {
        fx4 v = reinterpret_cast<fx4*>(out)[i] + reinterpret_cast<const fx4*>(parts)[i];
        reinterpret_cast<fx4*>(out)[i] = v;
    }
}

// ---------------------------------------------------------------------------
extern "C" void kernel_launch(void* const* d_in, const int* in_sizes, int n_in,
                              void* d_out, int out_size, void* d_ws, size_t ws_size,
                              hipStream_t stream)
{
    const float* hs = (const float*)d_in[0];
    const float* wq = (const float*)d_in[1];
    const float* wk = (const float*)d_in[2];
    const float* wv = (const float*)d_in[3];
    const float* wo = (const float*)d_in[4];
    const float* kc = (const float*)d_in[5];
    const float* vc = (const float*)d_in[6];
    const int* pos  = (const int*)d_in[7];
    const int* boff = (const int*)d_in[11];
    float* out = (float*)d_out;

    char* ws = (char*)d_ws;
    unsigned short* woTh  = (unsigned short*)(ws + 0);          // 32 MiB
    unsigned short* wqkvT = (unsigned short*)(ws + 67108864);   // 48 MiB (phase 1)
    unsigned short* kall  = (unsigned short*)(ws + 67108864);   // 16 MiB (phase 2)
    unsigned short* vTp   = (unsigned short*)(ws + 83886080);   // 16 MiB (phase 2)
    unsigned short* ohi   = (unsigned short*)(ws + 100663296);  //  8 MiB (phase 2)
    float* qkvb           = (float*)(ws + 117440512);           // 48 MiB (2 partials)
    float* oparts         = (float*)(ws + 117440512);           // 16 MiB (phase 2)
    unsigned short* hsb   = (unsigned short*)(ws + 167772160);  //  8 MiB (phase 1)
    unsigned short* qbb   = (unsigned short*)(ws + 167772160);  //  8 MiB (phase 2)
    float* tab            = (float*)(ws + 176160768);           // 128 KiB

    prep_kernel<<<12352, 256, 0, stream>>>(wq, wk, wv, wo, hs, wqkvT, woTh, hsb, tab);

    // QKV: [1024 x 6144 x 4096], split-K=2 -> 768 blocks (3/CU)
    qkv_gemm_kernel<<<768, 256, 0, stream>>>(
        hsb, wqkvT,
        qkvb, qkvb + (size_t)1024 * 6144, (size_t)1024 * 6144,
        4096, 6144, 64, 64, 8, 48, 2);

    rope_q_kernel<<<1024, 256, 0, stream>>>(qkvb, qkvb + 6291456, pos, tab, qbb);
    gather_kv_kernel<<<2048, 256, 0, stream>>>(qkvb, qkvb + 6291456, kc, vc, boff, tab, kall, vTp);
    attn_kernel<<<256, 512, 0, stream>>>(qbb, kall, vTp, ohi);

    // O-proj: [1024 x 4096 x 4096] bf16, split-K=2 -> 512 blocks
    oproj_gemm_kernel<<<512, 256, 0, stream>>>(
        ohi, woTh,
        out, oparts, (size_t)1024 * 4096,
        4096, 4096, 64, 64, 8, 32, 2);
    reduce_out_kernel<<<2048, 256, 0, stream>>>(out, oparts);
}

// Round 16
// 230.370 us; speedup vs baseline: 1.0109x; 1.0109x over previous
//
#include <hip/hip_runtime.h>

#define BSZ  4
#define QL   256
#define KVL  2048
#define HIST 1792
#define WIN  1024
#define NH   32
#define NKVH 8
#define DH   128
#define HID  4096
#define SCALE 0.088388347648318447f
#define MFIX  8.0f

typedef __bf16 bf16x8 __attribute__((ext_vector_type(8)));
typedef float  fx4    __attribute__((ext_vector_type(4)));
typedef unsigned short us4 __attribute__((ext_vector_type(4)));
typedef unsigned short us8 __attribute__((ext_vector_type(8)));

__device__ __forceinline__ unsigned short f2bf(float x) {
    unsigned u = __float_as_uint(x);
    u += 0x7FFFu + ((u >> 16) & 1u);   // round-to-nearest-even
    return (unsigned short)(u >> 16);
}
__device__ __forceinline__ float bf2f(unsigned short h) {
    return __uint_as_float(((unsigned)h) << 16);
}
__device__ __forceinline__ fx4 mfma16(bf16x8 a, bf16x8 b, fx4 c) {
    return __builtin_amdgcn_mfma_f32_16x16x32_bf16(a, b, c, 0, 0, 0);
}
__device__ __forceinline__ bf16x8 ldb16(const unsigned short* p) {
    return *reinterpret_cast<const bf16x8*>(p);
}

typedef __attribute__((address_space(1))) const void gv_t;
typedef __attribute__((address_space(3))) void lv_t;
__device__ __forceinline__ void gl16(const void* g, void* l) {
    __builtin_amdgcn_global_load_lds((gv_t*)g, (lv_t*)l, 16, 0, 0);
}

// ---------------------------------------------------------------------------
// Transpose one 64x64 tile: w f32 [K][N] -> blocked bf16 [n_blk][k_blk][64][64]
// (8KB contiguous per tile; store instrs are 1KB contiguous). f32 XOR-swizzled
// LDS (shf[n][k ^ (n&28)]): write 2-way (free), read uniform 8/bank.
// ---------------------------------------------------------------------------
__device__ __forceinline__ void transpose_tile(
    const float* __restrict__ w, unsigned short* __restrict__ hi, int N,
    int n0, int k0, float* shf /* [64*64] */)
{
    const int tid = threadIdx.x & 255;
    const int rr = tid >> 4;            // 0..15
    const int cc = (tid & 15) * 4;      // 0..60
#pragma unroll
    for (int p = 0; p < 4; ++p) {
        const int kl = p * 16 + rr;
        fx4 v = *reinterpret_cast<const fx4*>(w + (size_t)(k0 + kl) * N + n0 + cc);
#pragma unroll
        for (int j = 0; j < 4; ++j) {
            const int n = cc + j;
            shf[n * 64 + (kl ^ (n & 28))] = v[j];
        }
    }
    __syncthreads();
    unsigned short* ob = hi + (((size_t)(n0 >> 6)) * 64 + (k0 >> 6)) * 4096;
#pragma unroll
    for (int s = 0; s < 2; ++s) {
        const int c = s * 256 + tid;      // chunk 0..511 (8 shorts each)
        const int n = c >> 3;
        const int k8 = (c & 7) * 8;
        const int sw = n & 28;
        const int b0 = (k8 ^ (sw & 24)) | (sw & 4);
        fx4 v0 = *reinterpret_cast<const fx4*>(&shf[n * 64 + b0]);
        fx4 v1 = *reinterpret_cast<const fx4*>(&shf[n * 64 + (b0 ^ 4)]);
        us8 o;
#pragma unroll
        for (int j = 0; j < 4; ++j) {
            o[j]     = f2bf(v0[j]);
            o[4 + j] = f2bf(v1[j]);
        }
        *reinterpret_cast<us8*>(ob + c * 8) = o;
    }
}

// ---------------------------------------------------------------------------
// bf16 GEMM body: C = A[M x K] @ B^T, 128x128 tile, BK=32, mfma_16x16x32.
// B^T is BLOCKED [n_blk][k_blk][64][64] bf16. 3-buffer depth-2
// global_load_lds pipeline, XCD swizzle, split-K over bz.
// ---------------------------------------------------------------------------
__device__ __forceinline__ void gemm_body(
    const unsigned short* __restrict__ A, const unsigned short* __restrict__ B,
    float* __restrict__ C0, float* __restrict__ Cz, size_t czstride,
    int lda, int ldc, int ksteps, int klast, int nx, int ny, int nz,
    int bid, int nblocks, unsigned short* lds)
{
    constexpr int TILE = 128 * 32;            // ushorts per operand tile

    const int per = nblocks >> 3;
    const int t = (bid & 7) * per + (bid >> 3);
    const int bx = t % nx;
    const int by = (t / nx) % ny;
    const int bz = t / (nx * ny);

    const int row0 = bx * 128;
    const int col0 = by * 128;
    const int kbase = bz * ksteps * 32;
    const int nks = (bz == nz - 1) ? klast : ksteps;
    float* Cm = (bz == 0) ? C0 : (Cz + (size_t)(bz - 1) * czstride);

    const int tid  = threadIdx.x;
    const int lane = tid & 63;
    const int w    = tid >> 6;
    const int wr   = w >> 1, wc = w & 1;
    const int l16  = lane & 15;
    const int lg   = lane >> 4;
    const int r_in = lane >> 2;          // 0..15
    const int c8   = (lane & 3) * 8;     // 0,8,16,24 (bf16)

    fx4 acc[4][4] = {};

    auto STAGE = [&](int bufi, int kp) {
        unsigned short* Lb = lds + bufi * (2 * TILE);
#pragma unroll
        for (int i = 0; i < 2; ++i) {
            const int r = w * 32 + i * 16 + r_in;
            const int ldsb = (w * 2 + i) * 512;
            gl16(A + (size_t)(row0 + r) * lda + kp + c8, Lb + ldsb);
            const int cr = col0 + r;
            const size_t baddr = ((size_t)(cr >> 6) * 64 + (kp >> 6)) * 4096
                               + (cr & 63) * 64 + (kp & 63) + c8;
            gl16(B + baddr, Lb + TILE + ldsb);
        }
    };

    STAGE(0, kbase);
    STAGE(1, kbase + 32);
    for (int ks = 0; ks < nks; ++ks) {
        if (ks + 2 < nks) {
            STAGE((ks + 2) % 3, kbase + (ks + 2) * 32);
            asm volatile("s_waitcnt vmcnt(8)" ::: "memory");   // tile ks done
        } else if (ks + 1 < nks) {
            asm volatile("s_waitcnt vmcnt(4)" ::: "memory");
        } else {
            asm volatile("s_waitcnt vmcnt(0)" ::: "memory");
        }
        __builtin_amdgcn_s_barrier();
        __builtin_amdgcn_sched_barrier(0);

        const unsigned short* Lb = lds + (ks % 3) * (2 * TILE);
        const unsigned short* AhT = Lb;
        const unsigned short* BhT = Lb + TILE;

        bf16x8 af[4], bfv[4];
#pragma unroll
        for (int f = 0; f < 4; ++f) {
            af[f]  = ldb16(AhT + (wr * 64 + f * 16 + l16) * 32 + lg * 8);
            bfv[f] = ldb16(BhT + (wc * 64 + f * 16 + l16) * 32 + lg * 8);
        }
        __builtin_amdgcn_s_setprio(1);
#pragma unroll
        for (int fr = 0; fr < 4; ++fr)
#pragma unroll
            for (int fc = 0; fc < 4; ++fc)
                acc[fr][fc] = mfma16(af[fr], bfv[fc], acc[fr][fc]);
        __builtin_amdgcn_s_setprio(0);
        __builtin_amdgcn_sched_barrier(0);
        __builtin_amdgcn_s_barrier();
    }
#pragma unroll
    for (int fr = 0; fr < 4; ++fr)
#pragma unroll
        for (int fc = 0; fc < 4; ++fc) {
            const size_t rbase = (size_t)(row0 + wr * 64 + fr * 16 + lg * 4);
            const int col = col0 + wc * 64 + fc * 16 + l16;
#pragma unroll
            for (int r = 0; r < 4; ++r)
                Cm[(rbase + r) * ldc + col] = acc[fr][fc][r];
        }
}

// Fused: first 2048 blocks transpose wo (2 tiles each, hidden under the
// GEMM's idle HBM), remaining 768 blocks do the QKV GEMM. LDS unioned.
__global__ __launch_bounds__(256) void qkv_gemm_kernel(
    const unsigned short* __restrict__ A, const unsigned short* __restrict__ B,
    float* __restrict__ C0, float* __restrict__ Cz, size_t czstride,
    const float* __restrict__ wo, unsigned short* __restrict__ woTh)
{
    __shared__ __align__(16) unsigned short lds[3 * 2 * 128 * 32];   // 48 KB
    const int bid = blockIdx.x;
    if (bid < 2048) {
        // tiles bid and bid+2048: covers 0..4095 exactly once
        transpose_tile(wo, woTh, 4096, (bid & 63) * 64, (bid >> 6) * 64,
                       reinterpret_cast<float*>(lds));
        __syncthreads();
        const int t2 = bid + 2048;
        transpose_tile(wo, woTh, 4096, (t2 & 63) * 64, (t2 >> 6) * 64,
                       reinterpret_cast<float*>(lds));
    } else {
        gemm_body(A, B, C0, Cz, czstride, 4096, 6144, 64, 64, 8, 48, 2,
                  bid - 2048, 768, lds);
    }
}

__global__ __launch_bounds__(256) void oproj_gemm_kernel(
    const unsigned short* __restrict__ A, const unsigned short* __restrict__ B,
    float* __restrict__ C0, float* __restrict__ Cz, size_t czstride)
{
    __shared__ __align__(16) unsigned short lds[3 * 2 * 128 * 32];   // 48 KB
    gemm_body(A, B, C0, Cz, czstride, 4096, 4096, 64, 64, 8, 32, 2,
              blockIdx.x, 512, lds);
}

// ---------------------------------------------------------------------------
// Prep kernel: wq/wk/wv transposes + hs convert + sincos table.
// Ranges: [0,4096) wq, [4096,5120) wk, [5120,6144) wv, [6144,8192) hs,
// [8192,8256) sincos.
// ---------------------------------------------------------------------------
__global__ __launch_bounds__(256) void prep_kernel(
    const float* __restrict__ wq, const float* __restrict__ wk,
    const float* __restrict__ wv, const float* __restrict__ hs,
    unsigned short* __restrict__ wqkvT,
    unsigned short* __restrict__ hsb, float* __restrict__ tab)
{
    __shared__ __align__(16) float shf[64 * 64];
    const int r = blockIdx.x;
    const int tid = threadIdx.x;
    if (r < 4096) {
        transpose_tile(wq, wqkvT, 4096, (r & 63) * 64, (r >> 6) * 64, shf);
    } else if (r < 5120) {
        const int r2 = r - 4096;
        transpose_tile(wk, wqkvT + (size_t)4096 * 4096, 1024,
                       (r2 & 15) * 64, (r2 >> 4) * 64, shf);
    } else if (r < 6144) {
        const int r2 = r - 5120;
        transpose_tile(wv, wqkvT + (size_t)5120 * 4096, 1024,
                       (r2 & 15) * 64, (r2 >> 4) * 64, shf);
    } else if (r < 8192) {
        const int r2 = r - 6144;
        int i = r2 * 256 + tid;
#pragma unroll
        for (int rep = 0; rep < 2; ++rep) {
            fx4 v = reinterpret_cast<const fx4*>(hs)[i];
            us4 o;
#pragma unroll
            for (int j = 0; j < 4; ++j) o[j] = f2bf(v[j]);
            reinterpret_cast<us4*>(hsb)[i] = o;
            i += 524288;
        }
    } else {
        const int r2 = r - 8192;
        const int qi = r2 * 4 + (tid >> 6);
        const int jr = tid & 63;
        const float inv = powf(10000.f, -(float)jr * (1.f / 64.f));
        const float f = (float)(HIST + qi) * inv;
        float s, c;
        sincosf(f, &s, &c);
        tab[(qi * 64 + jr) * 2]     = c;
        tab[(qi * 64 + jr) * 2 + 1] = s;
    }
}

// ---------------------------------------------------------------------------
// RoPE on Q (adds split-K partials) -> bf16 [B][H][Q][D]
// ---------------------------------------------------------------------------
__global__ __launch_bounds__(256) void rope_q_kernel(
    const float* __restrict__ qkv0, const float* __restrict__ qkv1,
    const int* __restrict__ pos_ids, const float* __restrict__ tab,
    unsigned short* __restrict__ qb)
{
    const int t = blockIdx.x;             // 0..1023
    const int b = t >> 8;
    const int qi = t & 255;
    const int pi = pos_ids[t] - HIST;     // 0..255
    const int tid = threadIdx.x;
    const int h = tid >> 3;               // 0..31
    const int d0 = (tid & 7) * 8;         // 0..56
    const float* q0 = qkv0 + (size_t)t * 6144 + h * DH;
    const float* q1 = qkv1 + (size_t)t * 6144 + h * DH;
    float xl[8], xh[8];
    *reinterpret_cast<fx4*>(&xl[0]) = *reinterpret_cast<const fx4*>(q0 + d0)
                                    + *reinterpret_cast<const fx4*>(q1 + d0);
    *reinterpret_cast<fx4*>(&xl[4]) = *reinterpret_cast<const fx4*>(q0 + d0 + 4)
                                    + *reinterpret_cast<const fx4*>(q1 + d0 + 4);
    *reinterpret_cast<fx4*>(&xh[0]) = *reinterpret_cast<const fx4*>(q0 + d0 + 64)
                                    + *reinterpret_cast<const fx4*>(q1 + d0 + 64);
    *reinterpret_cast<fx4*>(&xh[4]) = *reinterpret_cast<const fx4*>(q0 + d0 + 68)
                                    + *reinterpret_cast<const fx4*>(q1 + d0 + 68);
    us8 outl, outh;
#pragma unroll
    for (int i = 0; i < 8; ++i) {
        const int jr = d0 + i;
        const float c = tab[(pi * 64 + jr) * 2];
        const float s = tab[(pi * 64 + jr) * 2 + 1];
        outl[i] = f2bf(xl[i] * c - xh[i] * s);
        outh[i] = f2bf(xh[i] * c + xl[i] * s);
    }
    unsigned short* dst = qb + (((size_t)b * NH + h) * QL + qi) * DH;
    *reinterpret_cast<us8*>(dst + d0)      = outl;
    *reinterpret_cast<us8*>(dst + d0 + 64) = outh;
}

// ---------------------------------------------------------------------------
// Gather KV, fully vectorized (float4 loads, 8 lanes/token), XCD-grouped.
//   k_all: [B][KVH][64 tiles][16 dchunks][32 kv][8] bf16 (chunked tiles)
//   vT:    [B][KVH][64 tiles][4 kvchunks][128 d][8 kv] bf16 (chunked tiles)
// ---------------------------------------------------------------------------
__global__ __launch_bounds__(256) void gather_kv_kernel(
    const float* __restrict__ qkv0, const float* __restrict__ qkv1,
    const float* __restrict__ k_cache, const float* __restrict__ v_cache,
    const int* __restrict__ block_offsets, const float* __restrict__ tab,
    unsigned short* __restrict__ k_all, unsigned short* __restrict__ vT)
{
    __shared__ unsigned short vls[32][136];
    const int bid = blockIdx.x;
    const int xcd = bid & 7;
    const int i = bid >> 3;               // 0..255
    const int g = ((i & 31) << 3) | xcd;  // token-chunk group
    const int kh = i >> 5;                // 0..7
    const int b  = g >> 6;
    const int ck = g & 63;
    const int kv0 = ck * 32;
    const int tid = threadIdx.x;
    const int tok = tid >> 3;             // 0..31
    const int sl  = tid & 7;              // 0..7 (d-slice)
    const int kvpos = kv0 + tok;
    const bool is_old = (kvpos < HIST);

    float x[16];
    float v[16];
    if (is_old) {
        const int blk = block_offsets[b * 32 + (kvpos >> 6)];
        const size_t base = (((size_t)blk * 64 + (kvpos & 63)) * NKVH + kh) * DH + sl * 4;
        const float* sk = k_cache + base;
        const float* sv = v_cache + base;
#pragma unroll
        for (int j = 0; j < 4; ++j) {
            *reinterpret_cast<fx4*>(&x[j * 4]) = *reinterpret_cast<const fx4*>(sk + j * 32);
            *reinterpret_cast<fx4*>(&v[j * 4]) = *reinterpret_cast<const fx4*>(sv + j * 32);
        }
    } else {
        const int t = b * QL + (kvpos - HIST);
        const int pi = kvpos - HIST;
        const size_t tb = (size_t)t * 6144 + kh * DH + sl * 4;
        const float* k0p = qkv0 + tb + 4096;
        const float* k1p = qkv1 + tb + 4096;
        const float* v0p = qkv0 + tb + 5120;
        const float* v1p = qkv1 + tb + 5120;
#pragma unroll
        for (int j = 0; j < 4; ++j) {
            *reinterpret_cast<fx4*>(&x[j * 4]) =
                *reinterpret_cast<const fx4*>(k0p + j * 32) +
                *reinterpret_cast<const fx4*>(k1p + j * 32);
            *reinterpret_cast<fx4*>(&v[j * 4]) =
                *reinterpret_cast<const fx4*>(v0p + j * 32) +
                *reinterpret_cast<const fx4*>(v1p + j * 32);
        }
#pragma unroll
        for (int j = 0; j < 2; ++j) {
            const int jr0 = sl * 4 + j * 32;
            fx4 cs0 = *reinterpret_cast<const fx4*>(tab + ((size_t)pi * 64 + jr0) * 2);
            fx4 cs1 = *reinterpret_cast<const fx4*>(tab + ((size_t)pi * 64 + jr0) * 2 + 4);
            const float c[4] = {cs0[0], cs0[2], cs1[0], cs1[2]};
            const float s[4] = {cs0[1], cs0[3], cs1[1], cs1[3]};
#pragma unroll
            for (int e = 0; e < 4; ++e) {
                const float lo = x[j * 4 + e], hi = x[(j + 2) * 4 + e];
                x[j * 4 + e]       = lo * c[e] - hi * s[e];
                x[(j + 2) * 4 + e] = hi * c[e] + lo * s[e];
            }
        }
    }
    {
        const size_t tbase = (((size_t)b * NKVH + kh) * KVL + kv0) * DH;
#pragma unroll
        for (int j = 0; j < 4; ++j) {
            const int d = sl * 4 + j * 32;
            const int dc = d >> 3;
            us4 pk;
#pragma unroll
            for (int e = 0; e < 4; ++e) pk[e] = f2bf(x[j * 4 + e]);
            *reinterpret_cast<us4*>(k_all + tbase + ((dc * 32 + tok) << 3) + (d & 7)) = pk;
        }
    }
#pragma unroll
    for (int j = 0; j < 4; ++j) {
        us4 pv;
#pragma unroll
        for (int e = 0; e < 4; ++e) pv[e] = f2bf(v[j * 4 + e]);
        *reinterpret_cast<us4*>(&vls[tok][sl * 4 + j * 32]) = pv;
    }
    __syncthreads();
    const int dr = tid >> 1;
    const int half = tid & 1;
    unsigned short* vtile = vT + (((size_t)b * NKVH + kh) * 64 + ck) * 4096;
#pragma unroll
    for (int i2 = 0; i2 < 16; i2 += 8) {
        const int kvc = half * 2 + (i2 >> 3);
        us8 pk;
#pragma unroll
        for (int j = 0; j < 8; ++j) pk[j] = vls[half * 16 + i2 + j][dr];
        *reinterpret_cast<us8*>(vtile + kvc * 1024 + dr * 8) = pk;
    }
}

// ---------------------------------------------------------------------------
// Flash attention (GQA, sliding window) -> bf16 output.
// 512-thread blocks = 2 q-heads sharing staged K/V; pair-processed kv tiles
// (4 LDS buffers, one lgkm fence per pair); fixed-max softmax (M=8);
// per-lane deferred lsum; GQA-aware XCD swizzle.
// ---------------------------------------------------------------------------
__global__ __launch_bounds__(512) void attn_kernel(
    const unsigned short* __restrict__ qb,
    const unsigned short* __restrict__ kall,
    const unsigned short* __restrict__ vT,
    unsigned short* __restrict__ ohi)
{
    __shared__ __align__(16) unsigned short ldskv[4 * 8192];
    __shared__ __align__(16) unsigned short plds[8][16][88];

    const int bid = blockIdx.x;              // 256 blocks
    const int xcd = bid & 7, slot = bid >> 3;
    const int pair = xcd * 4 + (slot >> 3);
    const int within = slot & 7;
    const int kh = pair >> 2, b = pair & 3;
    const int qt = within & 3, p = within >> 2;

    const int tid = threadIdx.x;
    const int lane = tid & 63;
    const int w = tid >> 6;
    const int h = kh * 4 + p * 2 + (w >> 2);
    const int ww = w & 3;
    const int l16 = lane & 15;
    const int lg = lane >> 4;
    const int qrow0 = qt * 64 + ww * 16;
    const int qabs0 = HIST + qrow0;

    const unsigned short* qptr =
        qb + (((size_t)b * NH + h) * QL + qrow0 + l16) * DH + lg * 8;
    bf16x8 qf[4];
#pragma unroll
    for (int ds = 0; ds < 4; ++ds) qf[ds] = ldb16(qptr + ds * 32);

    fx4 oacc[8];
#pragma unroll
    for (int f = 0; f < 8; ++f) oacc[f] = (fx4){0.f, 0.f, 0.f, 0.f};
    float lsum[4] = {0.f, 0.f, 0.f, 0.f};

    const unsigned short* kbase = kall + ((size_t)b * NKVH + kh) * (KVL * DH);
    const unsigned short* vbase = vT + ((size_t)b * NKVH + kh) * (KVL * DH);

    const int kv_lo = ((HIST + qt * 64) - (WIN - 1)) & ~31;   // 34 tiles of 32

    auto STAGE = [&](int bufi, int kv0) {
        unsigned short* kl = ldskv + bufi * 8192;
        const unsigned short* kg = kbase + (size_t)kv0 * DH;
        const unsigned short* vg = vbase + (size_t)(kv0 >> 5) * 4096;
        const int ci = w * 64 + lane;
        gl16(kg + ci * 8, kl + ci * 8);
        gl16(vg + ci * 8, kl + 4096 + ci * 8);
    };

    auto QK = [&](const unsigned short* kl, fx4& s0, fx4& s1) {
#pragma unroll
        for (int ds = 0; ds < 4; ++ds) {
            bf16x8 kf0 = ldb16(kl + ((ds * 4 + lg) * 32 + l16) * 8);
            bf16x8 kf1 = ldb16(kl + ((ds * 4 + lg) * 32 + 16 + l16) * 8);
            s0 = mfma16(qf[ds], kf0, s0);
            s1 = mfma16(qf[ds], kf1, s1);
        }
    };

    auto SM = [&](int kv0, fx4& s0, fx4& s1, int pc) {
        float p0v[4], p1v[4];
        const bool interior = (kv0 >= qabs0 + 16 - WIN) && (kv0 + 31 <= qabs0);
        if (interior) {
#pragma unroll
            for (int r = 0; r < 4; ++r) {
                p0v[r] = __expf(fmaf(s0[r], SCALE, -MFIX));
                p1v[r] = __expf(fmaf(s1[r], SCALE, -MFIX));
            }
        } else {
            const int kvp0 = kv0 + l16, kvp1 = kvp0 + 16;
#pragma unroll
            for (int r = 0; r < 4; ++r) {
                const int qpos = qabs0 + lg * 4 + r;
                const float e0 = __expf(fmaf(s0[r], SCALE, -MFIX));
                const float e1 = __expf(fmaf(s1[r], SCALE, -MFIX));
                p0v[r] = (kvp0 <= qpos && kvp0 > qpos - WIN) ? e0 : 0.f;
                p1v[r] = (kvp1 <= qpos && kvp1 > qpos - WIN) ? e1 : 0.f;
            }
        }
#pragma unroll
        for (int r = 0; r < 4; ++r) {
            lsum[r] += p0v[r] + p1v[r];
            plds[w][lg * 4 + r][pc + l16] = f2bf(p0v[r]);
            plds[w][lg * 4 + r][pc + 16 + l16] = f2bf(p1v[r]);
        }
    };

    auto PV = [&](const unsigned short* vl, bf16x8 pa) {
#pragma unroll
        for (int f = 0; f < 8; ++f) {
            bf16x8 vf = ldb16(vl + lg * 1024 + (f * 16 + l16) * 8);
            oacc[f] = mfma16(pa, vf, oacc[f]);
        }
    };

    STAGE(0, kv_lo);
    STAGE(1, kv_lo + 32);

    for (int t = 0; t < 34; t += 2) {
        if (t + 2 < 34) {
            STAGE((t + 2) & 3, kv_lo + (t + 2) * 32);
            STAGE((t + 3) & 3, kv_lo + (t + 3) * 32);
            asm volatile("s_waitcnt vmcnt(4)" ::: "memory");
        } else {
            asm volatile("s_waitcnt vmcnt(0)" ::: "memory");
        }
        __builtin_amdgcn_s_barrier();
        __builtin_amdgcn_sched_barrier(0);

        const unsigned short* kl0 = ldskv + (t & 3) * 8192;
        const unsigned short* kl1 = ldskv + ((t + 1) & 3) * 8192;

        fx4 sA0 = (fx4){0.f, 0.f, 0.f, 0.f}, sA1 = (fx4){0.f, 0.f, 0.f, 0.f};
        fx4 sB0 = (fx4){0.f, 0.f, 0.f, 0.f}, sB1 = (fx4){0.f, 0.f, 0.f, 0.f};
        __builtin_amdgcn_s_setprio(1);
        QK(kl0, sA0, sA1);
        QK(kl1, sB0, sB1);
        __builtin_amdgcn_s_setprio(0);

        SM(kv_lo + t * 32, sA0, sA1, 0);
        SM(kv_lo + (t + 1) * 32, sB0, sB1, 40);

        asm volatile("s_waitcnt lgkmcnt(0)" ::: "memory");
        __builtin_amdgcn_sched_barrier(0);
        bf16x8 pa0 = ldb16(&plds[w][l16][0 + lg * 8]);
        bf16x8 pa1 = ldb16(&plds[w][l16][40 + lg * 8]);
        __builtin_amdgcn_s_setprio(1);
        PV(kl0 + 4096, pa0);
        PV(kl1 + 4096, pa1);
        __builtin_amdgcn_s_setprio(0);
        __builtin_amdgcn_sched_barrier(0);
        __builtin_amdgcn_s_barrier();
    }
#pragma unroll
    for (int r = 0; r < 4; ++r) {
#pragma unroll
        for (int off = 1; off < 16; off <<= 1)
            lsum[r] += __shfl_xor(lsum[r], off);
    }
    float rl[4];
#pragma unroll
    for (int r = 0; r < 4; ++r) rl[r] = 1.f / lsum[r];
    const size_t obase = ((size_t)b * QL + qrow0 + lg * 4) * (NH * DH) + h * DH;
#pragma unroll
    for (int f = 0; f < 8; ++f)
#pragma unroll
        for (int r = 0; r < 4; ++r)
            ohi[obase + (size_t)r * (NH * DH) + f * 16 + l16] = f2bf(oacc[f][r] * rl[r]);
}

__global__ __launch_bounds__(256) void reduce_out_kernel(
    float* __restrict__ out, const float* __restrict__ parts)
{
    const int n4 = (1024 * 4096) / 4;
    int i = blockIdx.x * blockDim.x + threadIdx.x;
    for (; i < n4; i += gridDim.x * blockDim.x) {
        fx4 v = reinterpret_cast<fx4*>(out)[i] + reinterpret_cast<const fx4*>(parts)[i];
        reinterpret_cast<fx4*>(out)[i] = v;
    }
}

// ---------------------------------------------------------------------------
extern "C" void kernel_launch(void* const* d_in, const int* in_sizes, int n_in,
                              void* d_out, int out_size, void* d_ws, size_t ws_size,
                              hipStream_t stream)
{
    const float* hs = (const float*)d_in[0];
    const float* wq = (const float*)d_in[1];
    const float* wk = (const float*)d_in[2];
    const float* wv = (const float*)d_in[3];
    const float* wo = (const float*)d_in[4];
    const float* kc = (const float*)d_in[5];
    const float* vc = (const float*)d_in[6];
    const int* pos  = (const int*)d_in[7];
    const int* boff = (const int*)d_in[11];
    float* out = (float*)d_out;

    char* ws = (char*)d_ws;
    unsigned short* woTh  = (unsigned short*)(ws + 0);          // 32 MiB
    unsigned short* wqkvT = (unsigned short*)(ws + 67108864);   // 48 MiB (phase 1)
    unsigned short* kall  = (unsigned short*)(ws + 67108864);   // 16 MiB (phase 2)
    unsigned short* vTp   = (unsigned short*)(ws + 83886080);   // 16 MiB (phase 2)
    unsigned short* ohi   = (unsigned short*)(ws + 100663296);  //  8 MiB (phase 2)
    float* qkvb           = (float*)(ws + 117440512);           // 48 MiB (2 partials)
    float* oparts         = (float*)(ws + 117440512);           // 16 MiB (phase 2)
    unsigned short* hsb   = (unsigned short*)(ws + 167772160);  //  8 MiB (phase 1)
    unsigned short* qbb   = (unsigned short*)(ws + 167772160);  //  8 MiB (phase 2)
    float* tab            = (float*)(ws + 176160768);           // 128 KiB

    prep_kernel<<<8256, 256, 0, stream>>>(wq, wk, wv, hs, wqkvT, hsb, tab);

    // Fused: 2048 wo-transpose blocks (hidden under GEMM HBM idle) + 768
    // QKV GEMM blocks ([1024 x 6144 x 4096], split-K=2, 3/CU)
    qkv_gemm_kernel<<<2816, 256, 0, stream>>>(
        hsb, wqkvT,
        qkvb, qkvb + (size_t)1024 * 6144, (size_t)1024 * 6144,
        wo, woTh);

    rope_q_kernel<<<1024, 256, 0, stream>>>(qkvb, qkvb + 6291456, pos, tab, qbb);
    gather_kv_kernel<<<2048, 256, 0, stream>>>(qkvb, qkvb + 6291456, kc, vc, boff, tab, kall, vTp);
    attn_kernel<<<256, 512, 0, stream>>>(qbb, kall, vTp, ohi);

    // O-proj: [1024 x 4096 x 4096] bf16, split-K=2 -> 512 blocks
    oproj_gemm_kernel<<<512, 256, 0, stream>>>(
        ohi, woTh,
        out, oparts, (size_t)1024 * 4096);
    reduce_out_kernel<<<2048, 256, 0, stream>>>(out, oparts);
}

// Round 17
// 216.721 us; speedup vs baseline: 1.0746x; 1.0630x over previous
//
#include <hip/hip_runtime.h>

#define BSZ  4
#define QL   256
#define KVL  2048
#define HIST 1792
#define WIN  1024
#define NH   32
#define NKVH 8
#define DH   128
#define HID  4096
#define SCALE 0.088388347648318447f
#define MFIX  8.0f

typedef __bf16 bf16x8 __attribute__((ext_vector_type(8)));
typedef float  fx4    __attribute__((ext_vector_type(4)));
typedef unsigned short us4 __attribute__((ext_vector_type(4)));
typedef unsigned short us8 __attribute__((ext_vector_type(8)));

__device__ __forceinline__ unsigned short f2bf(float x) {
    unsigned u = __float_as_uint(x);
    u += 0x7FFFu + ((u >> 16) & 1u);   // round-to-nearest-even
    return (unsigned short)(u >> 16);
}
__device__ __forceinline__ float bf2f(unsigned short h) {
    return __uint_as_float(((unsigned)h) << 16);
}
__device__ __forceinline__ fx4 mfma16(bf16x8 a, bf16x8 b, fx4 c) {
    return __builtin_amdgcn_mfma_f32_16x16x32_bf16(a, b, c, 0, 0, 0);
}
__device__ __forceinline__ bf16x8 ldb16(const unsigned short* p) {
    return *reinterpret_cast<const bf16x8*>(p);
}

typedef __attribute__((address_space(1))) const void gv_t;
typedef __attribute__((address_space(3))) void lv_t;
__device__ __forceinline__ void gl16(const void* g, void* l) {
    __builtin_amdgcn_global_load_lds((gv_t*)g, (lv_t*)l, 16, 0, 0);
}

// ---------------------------------------------------------------------------
// bf16 GEMM body: C = A[M x K] @ W, 128x128 tile, BK=32, mfma_16x16x32.
// W (f32 [K][N]) is pre-converted to K-CHUNKED bf16: [K/8][N][8] -- the 8
// consecutive k's a B-fragment lane needs are 16B-contiguous, so both the
// converter and the GEMM staging are fully coalesced (no transpose anywhere).
// QKVB: B is the wq|wk|wv concatenation (block-uniform 3-way branch).
// 3-buffer depth-2 global_load_lds pipeline, XCD swizzle, split-K over bz.
// ---------------------------------------------------------------------------
template<bool QKVB>
__device__ __forceinline__ void gemm_body(
    const unsigned short* __restrict__ A, const unsigned short* __restrict__ B,
    float* __restrict__ C0, float* __restrict__ Cz, size_t czstride,
    int lda, int ldc, int ksteps, int klast, int nx, int ny, int nz,
    int bid, int nblocks, unsigned short* lds)
{
    constexpr int TILE = 128 * 32;            // ushorts per operand tile

    const int per = nblocks >> 3;
    const int t = (bid & 7) * per + (bid >> 3);
    const int bx = t % nx;
    const int by = (t / nx) % ny;
    const int bz = t / (nx * ny);

    const int row0 = bx * 128;
    const int col0 = by * 128;
    const int kbase = bz * ksteps * 32;
    const int nks = (bz == nz - 1) ? klast : ksteps;
    float* Cm = (bz == 0) ? C0 : (Cz + (size_t)(bz - 1) * czstride);

    // resolve which weight matrix this column tile lives in
    const unsigned short* Bm;
    int Nw, lc0;
    if (QKVB) {
        if (col0 < 4096)      { Bm = B;            Nw = 4096; lc0 = col0; }
        else if (col0 < 5120) { Bm = B + 16777216; Nw = 1024; lc0 = col0 - 4096; }
        else                  { Bm = B + 20971520; Nw = 1024; lc0 = col0 - 5120; }
    } else { Bm = B; Nw = 4096; lc0 = col0; }

    const int tid  = threadIdx.x;
    const int lane = tid & 63;
    const int w    = tid >> 6;
    const int wr   = w >> 1, wc = w & 1;
    const int l16  = lane & 15;
    const int lg   = lane >> 4;
    const int r_in = lane >> 2;          // 0..15
    const int c8   = (lane & 3) * 8;     // 0,8,16,24 (bf16)

    fx4 acc[4][4] = {};

    auto STAGE = [&](int bufi, int kp) {
        unsigned short* Lb = lds + bufi * (2 * TILE);
#pragma unroll
        for (int i = 0; i < 2; ++i) {
            // A: row-major [M][K]
            const int r = w * 32 + i * 16 + r_in;
            gl16(A + (size_t)(row0 + r) * lda + kp + c8,
                 Lb + (w * 2 + i) * 512);
            // B: k-chunked [K/8][Nw][8]; chunk c = kg*128 + n
            const int c = i * 256 + tid;
            const int kg = c >> 7;          // 0..3
            const int n  = c & 127;
            gl16(Bm + ((size_t)((kp >> 3) + kg) * Nw + lc0 + n) * 8,
                 Lb + TILE + (i * 256 + w * 64) * 8);
        }
    };

    STAGE(0, kbase);
    STAGE(1, kbase + 32);
    for (int ks = 0; ks < nks; ++ks) {
        if (ks + 2 < nks) {
            STAGE((ks + 2) % 3, kbase + (ks + 2) * 32);
            asm volatile("s_waitcnt vmcnt(8)" ::: "memory");   // tile ks done
        } else if (ks + 1 < nks) {
            asm volatile("s_waitcnt vmcnt(4)" ::: "memory");
        } else {
            asm volatile("s_waitcnt vmcnt(0)" ::: "memory");
        }
        __builtin_amdgcn_s_barrier();
        __builtin_amdgcn_sched_barrier(0);

        const unsigned short* Lb = lds + (ks % 3) * (2 * TILE);
        const unsigned short* AhT = Lb;
        const unsigned short* BhT = Lb + TILE;

        bf16x8 af[4], bfv[4];
#pragma unroll
        for (int f = 0; f < 4; ++f) {
            af[f]  = ldb16(AhT + (wr * 64 + f * 16 + l16) * 32 + lg * 8);
            bfv[f] = ldb16(BhT + (lg * 128 + wc * 64 + f * 16 + l16) * 8);
        }
        __builtin_amdgcn_s_setprio(1);
#pragma unroll
        for (int fr = 0; fr < 4; ++fr)
#pragma unroll
            for (int fc = 0; fc < 4; ++fc)
                acc[fr][fc] = mfma16(af[fr], bfv[fc], acc[fr][fc]);
        __builtin_amdgcn_s_setprio(0);
        __builtin_amdgcn_sched_barrier(0);
        __builtin_amdgcn_s_barrier();
    }
#pragma unroll
    for (int fr = 0; fr < 4; ++fr)
#pragma unroll
        for (int fc = 0; fc < 4; ++fc) {
            const size_t rbase = (size_t)(row0 + wr * 64 + fr * 16 + lg * 4);
            const int col = col0 + wc * 64 + fc * 16 + l16;
#pragma unroll
            for (int r = 0; r < 4; ++r)
                Cm[(rbase + r) * ldc + col] = acc[fr][fc][r];
        }
}

__global__ __launch_bounds__(256) void qkv_gemm_kernel(
    const unsigned short* __restrict__ A, const unsigned short* __restrict__ B,
    float* __restrict__ C0, float* __restrict__ Cz, size_t czstride)
{
    __shared__ __align__(16) unsigned short lds[3 * 2 * 128 * 32];   // 48 KB
    gemm_body<true>(A, B, C0, Cz, czstride, 4096, 6144, 64, 64, 8, 48, 2,
                    blockIdx.x, 768, lds);
}

__global__ __launch_bounds__(256) void oproj_gemm_kernel(
    const unsigned short* __restrict__ A, const unsigned short* __restrict__ B,
    float* __restrict__ C0, float* __restrict__ Cz, size_t czstride)
{
    __shared__ __align__(16) unsigned short lds[3 * 2 * 128 * 32];   // 48 KB
    gemm_body<false>(A, B, C0, Cz, czstride, 4096, 4096, 64, 64, 8, 32, 2,
                     blockIdx.x, 512, lds);
}

// ---------------------------------------------------------------------------
// Prep: pure streaming converts (no transpose, no LDS).
// Weights f32 [K][N] -> k-chunked bf16 [K/8][N][8]: thread t reads 8 rows at
// column n (each wave instr = 256B contiguous), writes one us8 (wave = 1KB
// contiguous). Ranges: wq [0,8192), wk [8192,10240), wv [10240,12288),
// wo [12288,20480), hs [20480,22528), sincos [22528,22592).
// ---------------------------------------------------------------------------
__device__ __forceinline__ void convert_w8(
    const float* __restrict__ w, unsigned short* __restrict__ out, int N,
    int kg, int n0)
{
    const int n = n0 + threadIdx.x;
    const float* src = w + (size_t)kg * 8 * N + n;
    us8 o;
#pragma unroll
    for (int j = 0; j < 8; ++j)
        o[j] = f2bf(src[(size_t)j * N]);
    *reinterpret_cast<us8*>(out + ((size_t)kg * N + n) * 8) = o;
}

__global__ __launch_bounds__(256) void prep_kernel(
    const float* __restrict__ wq, const float* __restrict__ wk,
    const float* __restrict__ wv, const float* __restrict__ wo,
    const float* __restrict__ hs,
    unsigned short* __restrict__ wqkvT, unsigned short* __restrict__ woTh,
    unsigned short* __restrict__ hsb, float* __restrict__ tab)
{
    const int r = blockIdx.x;
    const int tid = threadIdx.x;
    if (r < 8192) {
        convert_w8(wq, wqkvT, 4096, r >> 4, (r & 15) * 256);
    } else if (r < 10240) {
        const int r2 = r - 8192;
        convert_w8(wk, wqkvT + 16777216, 1024, r2 >> 2, (r2 & 3) * 256);
    } else if (r < 12288) {
        const int r2 = r - 10240;
        convert_w8(wv, wqkvT + 20971520, 1024, r2 >> 2, (r2 & 3) * 256);
    } else if (r < 20480) {
        const int r2 = r - 12288;
        convert_w8(wo, woTh, 4096, r2 >> 4, (r2 & 15) * 256);
    } else if (r < 22528) {
        const int r2 = r - 20480;
        int i = r2 * 256 + tid;
#pragma unroll
        for (int rep = 0; rep < 2; ++rep) {
            fx4 v = reinterpret_cast<const fx4*>(hs)[i];
            us4 o;
#pragma unroll
            for (int j = 0; j < 4; ++j) o[j] = f2bf(v[j]);
            reinterpret_cast<us4*>(hsb)[i] = o;
            i += 524288;
        }
    } else {
        const int r2 = r - 22528;
        const int qi = r2 * 4 + (tid >> 6);
        const int jr = tid & 63;
        const float inv = powf(10000.f, -(float)jr * (1.f / 64.f));
        const float f = (float)(HIST + qi) * inv;
        float s, c;
        sincosf(f, &s, &c);
        tab[(qi * 64 + jr) * 2]     = c;
        tab[(qi * 64 + jr) * 2 + 1] = s;
    }
}

// ---------------------------------------------------------------------------
// RoPE on Q (adds split-K partials) -> bf16 [B][H][Q][D]
// ---------------------------------------------------------------------------
__global__ __launch_bounds__(256) void rope_q_kernel(
    const float* __restrict__ qkv0, const float* __restrict__ qkv1,
    const int* __restrict__ pos_ids, const float* __restrict__ tab,
    unsigned short* __restrict__ qb)
{
    const int t = blockIdx.x;             // 0..1023
    const int b = t >> 8;
    const int qi = t & 255;
    const int pi = pos_ids[t] - HIST;     // 0..255
    const int tid = threadIdx.x;
    const int h = tid >> 3;               // 0..31
    const int d0 = (tid & 7) * 8;         // 0..56
    const float* q0 = qkv0 + (size_t)t * 6144 + h * DH;
    const float* q1 = qkv1 + (size_t)t * 6144 + h * DH;
    float xl[8], xh[8];
    *reinterpret_cast<fx4*>(&xl[0]) = *reinterpret_cast<const fx4*>(q0 + d0)
                                    + *reinterpret_cast<const fx4*>(q1 + d0);
    *reinterpret_cast<fx4*>(&xl[4]) = *reinterpret_cast<const fx4*>(q0 + d0 + 4)
                                    + *reinterpret_cast<const fx4*>(q1 + d0 + 4);
    *reinterpret_cast<fx4*>(&xh[0]) = *reinterpret_cast<const fx4*>(q0 + d0 + 64)
                                    + *reinterpret_cast<const fx4*>(q1 + d0 + 64);
    *reinterpret_cast<fx4*>(&xh[4]) = *reinterpret_cast<const fx4*>(q0 + d0 + 68)
                                    + *reinterpret_cast<const fx4*>(q1 + d0 + 68);
    us8 outl, outh;
#pragma unroll
    for (int i = 0; i < 8; ++i) {
        const int jr = d0 + i;
        const float c = tab[(pi * 64 + jr) * 2];
        const float s = tab[(pi * 64 + jr) * 2 + 1];
        outl[i] = f2bf(xl[i] * c - xh[i] * s);
        outh[i] = f2bf(xh[i] * c + xl[i] * s);
    }
    unsigned short* dst = qb + (((size_t)b * NH + h) * QL + qi) * DH;
    *reinterpret_cast<us8*>(dst + d0)      = outl;
    *reinterpret_cast<us8*>(dst + d0 + 64) = outh;
}

// ---------------------------------------------------------------------------
// Gather KV, fully vectorized (float4 loads, 8 lanes/token), XCD-grouped.
//   k_all: [B][KVH][64 tiles][16 dchunks][32 kv][8] bf16 (chunked tiles)
//   vT:    [B][KVH][64 tiles][4 kvchunks][128 d][8 kv] bf16 (chunked tiles)
// ---------------------------------------------------------------------------
__global__ __launch_bounds__(256) void gather_kv_kernel(
    const float* __restrict__ qkv0, const float* __restrict__ qkv1,
    const float* __restrict__ k_cache, const float* __restrict__ v_cache,
    const int* __restrict__ block_offsets, const float* __restrict__ tab,
    unsigned short* __restrict__ k_all, unsigned short* __restrict__ vT)
{
    __shared__ unsigned short vls[32][136];
    const int bid = blockIdx.x;
    const int xcd = bid & 7;
    const int i = bid >> 3;               // 0..255
    const int g = ((i & 31) << 3) | xcd;  // token-chunk group
    const int kh = i >> 5;                // 0..7
    const int b  = g >> 6;
    const int ck = g & 63;
    const int kv0 = ck * 32;
    const int tid = threadIdx.x;
    const int tok = tid >> 3;             // 0..31
    const int sl  = tid & 7;              // 0..7 (d-slice)
    const int kvpos = kv0 + tok;
    const bool is_old = (kvpos < HIST);

    float x[16];
    float v[16];
    if (is_old) {
        const int blk = block_offsets[b * 32 + (kvpos >> 6)];
        const size_t base = (((size_t)blk * 64 + (kvpos & 63)) * NKVH + kh) * DH + sl * 4;
        const float* sk = k_cache + base;
        const float* sv = v_cache + base;
#pragma unroll
        for (int j = 0; j < 4; ++j) {
            *reinterpret_cast<fx4*>(&x[j * 4]) = *reinterpret_cast<const fx4*>(sk + j * 32);
            *reinterpret_cast<fx4*>(&v[j * 4]) = *reinterpret_cast<const fx4*>(sv + j * 32);
        }
    } else {
        const int t = b * QL + (kvpos - HIST);
        const int pi = kvpos - HIST;
        const size_t tb = (size_t)t * 6144 + kh * DH + sl * 4;
        const float* k0p = qkv0 + tb + 4096;
        const float* k1p = qkv1 + tb + 4096;
        const float* v0p = qkv0 + tb + 5120;
        const float* v1p = qkv1 + tb + 5120;
#pragma unroll
        for (int j = 0; j < 4; ++j) {
            *reinterpret_cast<fx4*>(&x[j * 4]) =
                *reinterpret_cast<const fx4*>(k0p + j * 32) +
                *reinterpret_cast<const fx4*>(k1p + j * 32);
            *reinterpret_cast<fx4*>(&v[j * 4]) =
                *reinterpret_cast<const fx4*>(v0p + j * 32) +
                *reinterpret_cast<const fx4*>(v1p + j * 32);
        }
#pragma unroll
        for (int j = 0; j < 2; ++j) {
            const int jr0 = sl * 4 + j * 32;
            fx4 cs0 = *reinterpret_cast<const fx4*>(tab + ((size_t)pi * 64 + jr0) * 2);
            fx4 cs1 = *reinterpret_cast<const fx4*>(tab + ((size_t)pi * 64 + jr0) * 2 + 4);
            const float c[4] = {cs0[0], cs0[2], cs1[0], cs1[2]};
            const float s[4] = {cs0[1], cs0[3], cs1[1], cs1[3]};
#pragma unroll
            for (int e = 0; e < 4; ++e) {
                const float lo = x[j * 4 + e], hi = x[(j + 2) * 4 + e];
                x[j * 4 + e]       = lo * c[e] - hi * s[e];
                x[(j + 2) * 4 + e] = hi * c[e] + lo * s[e];
            }
        }
    }
    {
        const size_t tbase = (((size_t)b * NKVH + kh) * KVL + kv0) * DH;
#pragma unroll
        for (int j = 0; j < 4; ++j) {
            const int d = sl * 4 + j * 32;
            const int dc = d >> 3;
            us4 pk;
#pragma unroll
            for (int e = 0; e < 4; ++e) pk[e] = f2bf(x[j * 4 + e]);
            *reinterpret_cast<us4*>(k_all + tbase + ((dc * 32 + tok) << 3) + (d & 7)) = pk;
        }
    }
#pragma unroll
    for (int j = 0; j < 4; ++j) {
        us4 pv;
#pragma unroll
        for (int e = 0; e < 4; ++e) pv[e] = f2bf(v[j * 4 + e]);
        *reinterpret_cast<us4*>(&vls[tok][sl * 4 + j * 32]) = pv;
    }
    __syncthreads();
    const int dr = tid >> 1;
    const int half = tid & 1;
    unsigned short* vtile = vT + (((size_t)b * NKVH + kh) * 64 + ck) * 4096;
#pragma unroll
    for (int i2 = 0; i2 < 16; i2 += 8) {
        const int kvc = half * 2 + (i2 >> 3);
        us8 pk;
#pragma unroll
        for (int j = 0; j < 8; ++j) pk[j] = vls[half * 16 + i2 + j][dr];
        *reinterpret_cast<us8*>(vtile + kvc * 1024 + dr * 8) = pk;
    }
}

// ---------------------------------------------------------------------------
// Flash attention (GQA, sliding window) -> bf16 output.
// 512-thread blocks = 2 q-heads sharing staged K/V; pair-processed kv tiles
// (4 LDS buffers, one lgkm fence per pair); fixed-max softmax (M=8);
// per-lane deferred lsum; GQA-aware XCD swizzle.
// ---------------------------------------------------------------------------
__global__ __launch_bounds__(512) void attn_kernel(
    const unsigned short* __restrict__ qb,
    const unsigned short* __restrict__ kall,
    const unsigned short* __restrict__ vT,
    unsigned short* __restrict__ ohi)
{
    __shared__ __align__(16) unsigned short ldskv[4 * 8192];
    __shared__ __align__(16) unsigned short plds[8][16][88];

    const int bid = blockIdx.x;              // 256 blocks
    const int xcd = bid & 7, slot = bid >> 3;
    const int pair = xcd * 4 + (slot >> 3);
    const int within = slot & 7;
    const int kh = pair >> 2, b = pair & 3;
    const int qt = within & 3, p = within >> 2;

    const int tid = threadIdx.x;
    const int lane = tid & 63;
    const int w = tid >> 6;
    const int h = kh * 4 + p * 2 + (w >> 2);
    const int ww = w & 3;
    const int l16 = lane & 15;
    const int lg = lane >> 4;
    const int qrow0 = qt * 64 + ww * 16;
    const int qabs0 = HIST + qrow0;

    const unsigned short* qptr =
        qb + (((size_t)b * NH + h) * QL + qrow0 + l16) * DH + lg * 8;
    bf16x8 qf[4];
#pragma unroll
    for (int ds = 0; ds < 4; ++ds) qf[ds] = ldb16(qptr + ds * 32);

    fx4 oacc[8];
#pragma unroll
    for (int f = 0; f < 8; ++f) oacc[f] = (fx4){0.f, 0.f, 0.f, 0.f};
    float lsum[4] = {0.f, 0.f, 0.f, 0.f};

    const unsigned short* kbase = kall + ((size_t)b * NKVH + kh) * (KVL * DH);
    const unsigned short* vbase = vT + ((size_t)b * NKVH + kh) * (KVL * DH);

    const int kv_lo = ((HIST + qt * 64) - (WIN - 1)) & ~31;   // 34 tiles of 32

    auto STAGE = [&](int bufi, int kv0) {
        unsigned short* kl = ldskv + bufi * 8192;
        const unsigned short* kg = kbase + (size_t)kv0 * DH;
        const unsigned short* vg = vbase + (size_t)(kv0 >> 5) * 4096;
        const int ci = w * 64 + lane;
        gl16(kg + ci * 8, kl + ci * 8);
        gl16(vg + ci * 8, kl + 4096 + ci * 8);
    };

    auto QK = [&](const unsigned short* kl, fx4& s0, fx4& s1) {
#pragma unroll
        for (int ds = 0; ds < 4; ++ds) {
            bf16x8 kf0 = ldb16(kl + ((ds * 4 + lg) * 32 + l16) * 8);
            bf16x8 kf1 = ldb16(kl + ((ds * 4 + lg) * 32 + 16 + l16) * 8);
            s0 = mfma16(qf[ds], kf0, s0);
            s1 = mfma16(qf[ds], kf1, s1);
        }
    };

    auto SM = [&](int kv0, fx4& s0, fx4& s1, int pc) {
        float p0v[4], p1v[4];
        const bool interior = (kv0 >= qabs0 + 16 - WIN) && (kv0 + 31 <= qabs0);
        if (interior) {
#pragma unroll
            for (int r = 0; r < 4; ++r) {
                p0v[r] = __expf(fmaf(s0[r], SCALE, -MFIX));
                p1v[r] = __expf(fmaf(s1[r], SCALE, -MFIX));
            }
        } else {
            const int kvp0 = kv0 + l16, kvp1 = kvp0 + 16;
#pragma unroll
            for (int r = 0; r < 4; ++r) {
                const int qpos = qabs0 + lg * 4 + r;
                const float e0 = __expf(fmaf(s0[r], SCALE, -MFIX));
                const float e1 = __expf(fmaf(s1[r], SCALE, -MFIX));
                p0v[r] = (kvp0 <= qpos && kvp0 > qpos - WIN) ? e0 : 0.f;
                p1v[r] = (kvp1 <= qpos && kvp1 > qpos - WIN) ? e1 : 0.f;
            }
        }
#pragma unroll
        for (int r = 0; r < 4; ++r) {
            lsum[r] += p0v[r] + p1v[r];
            plds[w][lg * 4 + r][pc + l16] = f2bf(p0v[r]);
            plds[w][lg * 4 + r][pc + 16 + l16] = f2bf(p1v[r]);
        }
    };

    auto PV = [&](const unsigned short* vl, bf16x8 pa) {
#pragma unroll
        for (int f = 0; f < 8; ++f) {
            bf16x8 vf = ldb16(vl + lg * 1024 + (f * 16 + l16) * 8);
            oacc[f] = mfma16(pa, vf, oacc[f]);
        }
    };

    STAGE(0, kv_lo);
    STAGE(1, kv_lo + 32);

    for (int t = 0; t < 34; t += 2) {
        if (t + 2 < 34) {
            STAGE((t + 2) & 3, kv_lo + (t + 2) * 32);
            STAGE((t + 3) & 3, kv_lo + (t + 3) * 32);
            asm volatile("s_waitcnt vmcnt(4)" ::: "memory");
        } else {
            asm volatile("s_waitcnt vmcnt(0)" ::: "memory");
        }
        __builtin_amdgcn_s_barrier();
        __builtin_amdgcn_sched_barrier(0);

        const unsigned short* kl0 = ldskv + (t & 3) * 8192;
        const unsigned short* kl1 = ldskv + ((t + 1) & 3) * 8192;

        fx4 sA0 = (fx4){0.f, 0.f, 0.f, 0.f}, sA1 = (fx4){0.f, 0.f, 0.f, 0.f};
        fx4 sB0 = (fx4){0.f, 0.f, 0.f, 0.f}, sB1 = (fx4){0.f, 0.f, 0.f, 0.f};
        __builtin_amdgcn_s_setprio(1);
        QK(kl0, sA0, sA1);
        QK(kl1, sB0, sB1);
        __builtin_amdgcn_s_setprio(0);

        SM(kv_lo + t * 32, sA0, sA1, 0);
        SM(kv_lo + (t + 1) * 32, sB0, sB1, 40);

        asm volatile("s_waitcnt lgkmcnt(0)" ::: "memory");
        __builtin_amdgcn_sched_barrier(0);
        bf16x8 pa0 = ldb16(&plds[w][l16][0 + lg * 8]);
        bf16x8 pa1 = ldb16(&plds[w][l16][40 + lg * 8]);
        __builtin_amdgcn_s_setprio(1);
        PV(kl0 + 4096, pa0);
        PV(kl1 + 4096, pa1);
        __builtin_amdgcn_s_setprio(0);
        __builtin_amdgcn_sched_barrier(0);
        __builtin_amdgcn_s_barrier();
    }
#pragma unroll
    for (int r = 0; r < 4; ++r) {
#pragma unroll
        for (int off = 1; off < 16; off <<= 1)
            lsum[r] += __shfl_xor(lsum[r], off);
    }
    float rl[4];
#pragma unroll
    for (int r = 0; r < 4; ++r) rl[r] = 1.f / lsum[r];
    const size_t obase = ((size_t)b * QL + qrow0 + lg * 4) * (NH * DH) + h * DH;
#pragma unroll
    for (int f = 0; f < 8; ++f)
#pragma unroll
        for (int r = 0; r < 4; ++r)
            ohi[obase + (size_t)r * (NH * DH) + f * 16 + l16] = f2bf(oacc[f][r] * rl[r]);
}

__global__ __launch_bounds__(256) void reduce_out_kernel(
    float* __restrict__ out, const float* __restrict__ parts)
{
    const int n4 = (1024 * 4096) / 4;
    int i = blockIdx.x * blockDim.x + threadIdx.x;
    for (; i < n4; i += gridDim.x * blockDim.x) {
        fx4 v = reinterpret_cast<fx4*>(out)[i] + reinterpret_cast<const fx4*>(parts)[i];
        reinterpret_cast<fx4*>(out)[i] = v;
    }
}

// ---------------------------------------------------------------------------
extern "C" void kernel_launch(void* const* d_in, const int* in_sizes, int n_in,
                              void* d_out, int out_size, void* d_ws, size_t ws_size,
                              hipStream_t stream)
{
    const float* hs = (const float*)d_in[0];
    const float* wq = (const float*)d_in[1];
    const float* wk = (const float*)d_in[2];
    const float* wv = (const float*)d_in[3];
    const float* wo = (const float*)d_in[4];
    const float* kc = (const float*)d_in[5];
    const float* vc = (const float*)d_in[6];
    const int* pos  = (const int*)d_in[7];
    const int* boff = (const int*)d_in[11];
    float* out = (float*)d_out;

    char* ws = (char*)d_ws;
    unsigned short* woTh  = (unsigned short*)(ws + 0);          // 32 MiB
    unsigned short* wqkvT = (unsigned short*)(ws + 67108864);   // 48 MiB (phase 1)
    unsigned short* kall  = (unsigned short*)(ws + 67108864);   // 16 MiB (phase 2)
    unsigned short* vTp   = (unsigned short*)(ws + 83886080);   // 16 MiB (phase 2)
    unsigned short* ohi   = (unsigned short*)(ws + 100663296);  //  8 MiB (phase 2)
    float* qkvb           = (float*)(ws + 117440512);           // 48 MiB (2 partials)
    float* oparts         = (float*)(ws + 117440512);           // 16 MiB (phase 2)
    unsigned short* hsb   = (unsigned short*)(ws + 167772160);  //  8 MiB (phase 1)
    unsigned short* qbb   = (unsigned short*)(ws + 167772160);  //  8 MiB (phase 2)
    float* tab            = (float*)(ws + 176160768);           // 128 KiB

    prep_kernel<<<22592, 256, 0, stream>>>(wq, wk, wv, wo, hs, wqkvT, woTh, hsb, tab);

    // QKV: [1024 x 6144 x 4096], split-K=2 -> 768 blocks (3/CU)
    qkv_gemm_kernel<<<768, 256, 0, stream>>>(
        hsb, wqkvT,
        qkvb, qkvb + (size_t)1024 * 6144, (size_t)1024 * 6144);

    rope_q_kernel<<<1024, 256, 0, stream>>>(qkvb, qkvb + 6291456, pos, tab, qbb);
    gather_kv_kernel<<<2048, 256, 0, stream>>>(qkvb, qkvb + 6291456, kc, vc, boff, tab, kall, vTp);
    attn_kernel<<<256, 512, 0, stream>>>(qbb, kall, vTp, ohi);

    // O-proj: [1024 x 4096 x 4096] bf16, split-K=2 -> 512 blocks
    oproj_gemm_kernel<<<512, 256, 0, stream>>>(
        ohi, woTh,
        out, oparts, (size_t)1024 * 4096);
    reduce_out_kernel<<<2048, 256, 0, stream>>>(out, oparts);
}